// Round 10
// baseline (805.620 us; speedup 1.0000x reference)
//
#include <hip/hip_runtime.h>
#include <math.h>

// ---- problem constants ----
#define B_      2
#define EMB_    384
#define NH_     8
#define HD_     48
#define NTOK    1729       // NPATCH + 1
#define NPATCH_ 1728
#define MLP_    1536
#define NL_     6
#define NC_     2
#define BSTR    1792       // per-batch row stride (padded tokens)
#define M_PAD   3584       // 2 * BSTR
#define SCALE2_ 0.20823661461464808f   // (1/sqrt(48)) * log2(e)
#define OPSZ    ((size_t)B_ * BSTR * EMB_)

typedef __bf16 bf16x8 __attribute__((ext_vector_type(8)));
typedef float floatx4 __attribute__((ext_vector_type(4)));
typedef _Float16 halfx4 __attribute__((ext_vector_type(4)));
typedef unsigned short u16;

__device__ __forceinline__ u16 f2b(float f) {
    unsigned int u = __float_as_uint(f);
    return (u16)((u + 0x7FFFu + ((u >> 16) & 1u)) >> 16);
}
__device__ __forceinline__ float b2f(u16 u) {
    return __uint_as_float(((unsigned int)u) << 16);
}
__device__ __forceinline__ u16 f2h(float f) {
    _Float16 h = (_Float16)f;
    return __builtin_bit_cast(unsigned short, h);
}
__device__ __forceinline__ bf16x8 ld8(const u16* p) {       // 16B-aligned
    return *(const bf16x8*)p;
}

// ============================================================
// Merged fp32 -> bf16 convert: conv_w | x | qkv_w | proj_w | mlp_w1 | mlp_w2
// ============================================================
#define CW_N  196608      // 384*512
#define P0_   196608
#define P1_   1966080     // + x (1769472)
#define P2_   4620288     // + qkv_w (2654208)
#define P3_   5505024     // + proj_w (884736)
#define P4_   9043968     // + mlp_w1 (3538944)
#define P5_   12582912    // + mlp_w2 (3538944)
__global__ __launch_bounds__(256) void cvt_all(
    const float* __restrict__ cw, const float* __restrict__ x,
    const float* __restrict__ qw, const float* __restrict__ pw,
    const float* __restrict__ w1, const float* __restrict__ w2,
    u16* __restrict__ cwb, u16* __restrict__ xb, u16* __restrict__ qwb,
    u16* __restrict__ pwb, u16* __restrict__ w1b, u16* __restrict__ w2b)
{
    int i = (blockIdx.x * 256 + threadIdx.x) * 4;
    const float* s; u16* d; int off;
    if      (i < P0_) { s = cw; d = cwb; off = 0; }
    else if (i < P1_) { s = x;  d = xb;  off = P0_; }
    else if (i < P2_) { s = qw; d = qwb; off = P1_; }
    else if (i < P3_) { s = pw; d = pwb; off = P2_; }
    else if (i < P4_) { s = w1; d = w1b; off = P3_; }
    else              { s = w2; d = w2b; off = P4_; }
    i -= off;
    float4 v = *(const float4*)(s + i);
    ushort4 o;
    o.x = f2b(v.x); o.y = f2b(v.y); o.z = f2b(v.z); o.w = f2b(v.w);
    *(ushort4*)(d + i) = o;
}

// ============================================================
// Patch embed as bf16 MFMA GEMM. grid (6, 54), block 256.
// ============================================================
__global__ __launch_bounds__(256) void patch_mfma(
    const u16* __restrict__ xb, const u16* __restrict__ cwb,
    const float* __restrict__ cb, const float* __restrict__ cls,
    const float* __restrict__ pos, float* __restrict__ t)
{
    __shared__ __align__(16) u16 As[64][40];
    __shared__ __align__(16) u16 Bs[64][40];
    const int tid  = threadIdx.x;
    const int lane = tid & 63, w = tid >> 6;
    const int wm = (w >> 1) * 32, wn = (w & 1) * 32;
    const int m0g = blockIdx.y * 64, n0g = blockIdx.x * 64;
    const int cl = lane & 15, kh = (lane >> 4) * 8;

    if (blockIdx.x == 0 && blockIdx.y == 0) {
        for (int c = tid; c < 2 * EMB_; c += 256) {
            int bb = c / EMB_, e = c % EMB_;
            t[(size_t)bb * BSTR * EMB_ + e] = cls[e] + pos[e];
        }
    }

    const int sm = tid >> 2, skc = tid & 3;
    const int gm_s = m0g + sm;
    const int bb_s = gm_s / 1728, p_s = gm_s % 1728;
    const int pz = p_s / 144, py = (p_s / 12) % 12, px = p_s % 12;

    floatx4 acc[2][2];
#pragma unroll
    for (int i = 0; i < 2; ++i)
#pragma unroll
        for (int j = 0; j < 2; ++j) acc[i][j] = (floatx4){0.f, 0.f, 0.f, 0.f};

    for (int k0 = 0; k0 < 512; k0 += 32) {
        {
            int k = k0 + skc * 8;
            int dz = k >> 6, dy = (k >> 3) & 7;
            *(uint4*)&As[sm][skc * 8] =
                *(const uint4*)(xb + ((size_t)(bb_s * 96 + pz * 8 + dz) * 96 +
                                      py * 8 + dy) * 96 + px * 8);
            *(uint4*)&Bs[sm][skc * 8] =
                *(const uint4*)(cwb + (size_t)(n0g + sm) * 512 + k);
        }
        __syncthreads();
        bf16x8 af[2], bfr[2];
#pragma unroll
        for (int i = 0; i < 2; ++i) af[i] = ld8(&As[wm + 16 * i + cl][kh]);
#pragma unroll
        for (int j = 0; j < 2; ++j) bfr[j] = ld8(&Bs[wn + 16 * j + cl][kh]);
#pragma unroll
        for (int i = 0; i < 2; ++i)
#pragma unroll
            for (int j = 0; j < 2; ++j)
                acc[i][j] = __builtin_amdgcn_mfma_f32_16x16x32_bf16(
                    af[i], bfr[j], acc[i][j], 0, 0, 0);
        __syncthreads();
    }

    const int r0 = (lane >> 4) * 4;
#pragma unroll
    for (int j = 0; j < 2; ++j) {
        int gn = n0g + wn + 16 * j + cl;
        float bn = cb[gn];
#pragma unroll
        for (int i = 0; i < 2; ++i) {
#pragma unroll
            for (int r = 0; r < 4; ++r) {
                int gm = m0g + wm + 16 * i + r0 + r;
                int bb = gm / 1728, p = gm % 1728;
                t[((size_t)bb * BSTR + 1 + p) * EMB_ + gn] =
                    acc[i][j][r] + bn + pos[(size_t)(1 + p) * EMB_ + gn];
            }
        }
    }
}

// ============================================================
// LayerNorm (only layer 0's LN1): one wave per row; emits bf16.
// ============================================================
__global__ __launch_bounds__(256) void ln_kernel(
    const float* __restrict__ x, const float* __restrict__ w,
    const float* __restrict__ b, u16* __restrict__ y)
{
    const int wave = threadIdx.x >> 6;
    const int lane = threadIdx.x & 63;
    const int tok  = blockIdx.x * 4 + wave;
    if (tok >= NTOK) return;
    const size_t row = (size_t)blockIdx.y * BSTR + tok;
    const float* xr = x + row * EMB_;

    float v[6];
    float s = 0.f;
#pragma unroll
    for (int j = 0; j < 6; ++j) { v[j] = xr[lane + 64 * j]; s += v[j]; }
#pragma unroll
    for (int off = 32; off; off >>= 1) s += __shfl_xor(s, off, 64);
    const float mean = s * (1.0f / EMB_);

    float q = 0.f;
#pragma unroll
    for (int j = 0; j < 6; ++j) { float d = v[j] - mean; q += d * d; }
#pragma unroll
    for (int off = 32; off; off >>= 1) q += __shfl_xor(q, off, 64);
    const float rstd = rsqrtf(q * (1.0f / EMB_) + 1e-5f);

    u16* yr = y + row * EMB_;
#pragma unroll
    for (int j = 0; j < 6; ++j) {
        int e = lane + 64 * j;
        yr[e] = f2b((v[j] - mean) * rstd * w[e] + b[e]);
    }
}

// ============================================================
// bf16 MFMA GEMM v2: BK=64, LDS stride 72. Tile 64x128 (2x2 waves).
// Cb (bf16) = act(A@W^T + bias); VT=1 routes cols [768,1152)
// transposed (f16) into vt for attention V.
// ============================================================
template<int FI, int FJ, int ACT, int VT>
__global__ __launch_bounds__(256) void gemm2(
    const u16* __restrict__ A, const u16* __restrict__ W,
    const float* __restrict__ bias, u16* __restrict__ Cb,
    u16* __restrict__ vt, int N, int K)
{
    constexpr int TM = 32 * FI;
    constexpr int TN = 32 * FJ;
    __shared__ __align__(16) u16 As[TM][72];
    __shared__ __align__(16) u16 Bs[TN][72];
    const int tid  = threadIdx.x;
    const int lane = tid & 63, w = tid >> 6;
    const int wm = (w >> 1) * (16 * FI);
    const int wn = (w & 1) * (16 * FJ);
    const int m0g = blockIdx.y * TM, n0g = blockIdx.x * TN;
    const int cl = lane & 15, kh = (lane >> 4) * 8;

    floatx4 acc[FI][FJ];
#pragma unroll
    for (int i = 0; i < FI; ++i)
#pragma unroll
        for (int j = 0; j < FJ; ++j)
            acc[i][j] = (floatx4){0.f, 0.f, 0.f, 0.f};

    for (int k0 = 0; k0 < K; k0 += 64) {
#pragma unroll
        for (int u = 0; u < TM / 32; ++u) {
            int c = tid + u * 256;
            int m = c >> 3, kc = c & 7;
            *(uint4*)&As[m][kc * 8] =
                *(const uint4*)(A + (size_t)(m0g + m) * K + k0 + kc * 8);
        }
#pragma unroll
        for (int u = 0; u < TN / 32; ++u) {
            int c = tid + u * 256;
            int n = c >> 3, kc = c & 7;
            *(uint4*)&Bs[n][kc * 8] =
                *(const uint4*)(W + (size_t)(n0g + n) * K + k0 + kc * 8);
        }
        __syncthreads();

        bf16x8 af[FI][2], bfr[FJ][2];
#pragma unroll
        for (int i = 0; i < FI; ++i) {
            af[i][0] = ld8(&As[wm + 16 * i + cl][kh]);
            af[i][1] = ld8(&As[wm + 16 * i + cl][32 + kh]);
        }
#pragma unroll
        for (int j = 0; j < FJ; ++j) {
            bfr[j][0] = ld8(&Bs[wn + 16 * j + cl][kh]);
            bfr[j][1] = ld8(&Bs[wn + 16 * j + cl][32 + kh]);
        }
#pragma unroll
        for (int i = 0; i < FI; ++i)
#pragma unroll
            for (int j = 0; j < FJ; ++j) {
                acc[i][j] = __builtin_amdgcn_mfma_f32_16x16x32_bf16(
                    af[i][0], bfr[j][0], acc[i][j], 0, 0, 0);
                acc[i][j] = __builtin_amdgcn_mfma_f32_16x16x32_bf16(
                    af[i][1], bfr[j][1], acc[i][j], 0, 0, 0);
            }
        __syncthreads();
    }

    const int r0 = (lane >> 4) * 4;
#pragma unroll
    for (int j = 0; j < FJ; ++j) {
        int gn = n0g + wn + 16 * j + cl;
        float bn = bias[gn];
#pragma unroll
        for (int i = 0; i < FI; ++i) {
            int gm0 = m0g + wm + 16 * i + r0;
            float v[4];
#pragma unroll
            for (int r = 0; r < 4; ++r) {
                float vv = acc[i][j][r] + bn;
                if (ACT) vv = 0.5f * vv * (1.0f + erff(vv * 0.70710678118654752f));
                v[r] = vv;
            }
            if (VT && gn >= 768) {
                int hh = (gn - 768) / 48, dd = (gn - 768) % 48;
                int bb = gm0 / BSTR, tok = gm0 - bb * BSTR;
                ushort4 o;
                o.x = f2h(v[0]); o.y = f2h(v[1]);
                o.z = f2h(v[2]); o.w = f2h(v[3]);
                *(ushort4*)(vt + ((size_t)(bb * 8 + hh) * 48 + dd) * BSTR + tok) = o;
            } else {
#pragma unroll
                for (int r = 0; r < 4; ++r)
                    Cb[(size_t)(gm0 + r) * N + gn] = f2b(v[r]);
            }
        }
    }
}

// ============================================================
// Full-row residual GEMM + fused epilogue LayerNorm.
//   T[32 rows] += A @ W^T + bias;   h = LN(T) (bf16, lnw/lnb)
// TM=32, TN=384 (full width -> one block owns whole rows:
// combine & LN computed exactly once per element). BK=64.
// COMB=1: A = bf16((op0+op1)/(l0+l1)) staged on the fly (attn splits).
// grid 112 blocks, 256 threads (2x2 waves: 16 rows x 192 cols each).
// LDS ~59 KB -> 2 blocks/CU.
// ============================================================
template<int COMB, int KK>
__global__ __launch_bounds__(256) void gemm_row(
    const u16* __restrict__ A, const u16* __restrict__ op,
    const float* __restrict__ lp, const u16* __restrict__ W,
    const float* __restrict__ bias, float* __restrict__ T,
    const float* __restrict__ lnw, const float* __restrict__ lnb,
    u16* __restrict__ h)
{
    __shared__ __align__(16) u16 As[32][72];
    __shared__ __align__(16) u16 Bs[384][72];
    __shared__ float redS[2][32], redQ[2][32];
    const int tid  = threadIdx.x;
    const int lane = tid & 63, w = tid >> 6;
    const int wm = (w >> 1) * 16;      // 0 | 16
    const int wn = (w & 1) * 192;      // 0 | 192
    const int m0g = blockIdx.x * 32;
    const int cl = lane & 15, quad = lane >> 4, kh = quad * 8;

    floatx4 acc[12];
#pragma unroll
    for (int j = 0; j < 12; ++j) acc[j] = (floatx4){0.f, 0.f, 0.f, 0.f};

    // A-staging coords: 32 rows x 8 chunks = 256, one chunk/thread
    const int am = tid >> 3, akc = tid & 7;
    const int arow = m0g + am;

    for (int k0 = 0; k0 < KK; k0 += 64) {
        {
            int kg = k0 + akc * 8;
            if (COMB) {
                int hh = kg / 48;                       // chunk within one head
                const u16* o0 = op + (size_t)arow * EMB_ + kg;
                ushort4 x0 = *(const ushort4*)o0;
                ushort4 x1 = *(const ushort4*)(o0 + 4);
                ushort4 y0 = *(const ushort4*)(o0 + OPSZ);
                ushort4 y1 = *(const ushort4*)(o0 + OPSZ + 4);
                halfx4 a0 = __builtin_bit_cast(halfx4, x0);
                halfx4 a1 = __builtin_bit_cast(halfx4, x1);
                halfx4 b0 = __builtin_bit_cast(halfx4, y0);
                halfx4 b1 = __builtin_bit_cast(halfx4, y1);
                float l0 = lp[(size_t)arow * NH_ + hh];
                float l1 = lp[((size_t)M_PAD + arow) * NH_ + hh];
                float rinv = 1.0f / (l0 + l1);
                ushort4 lo, hi;
                lo.x = f2b(((float)a0[0] + (float)b0[0]) * rinv);
                lo.y = f2b(((float)a0[1] + (float)b0[1]) * rinv);
                lo.z = f2b(((float)a0[2] + (float)b0[2]) * rinv);
                lo.w = f2b(((float)a0[3] + (float)b0[3]) * rinv);
                hi.x = f2b(((float)a1[0] + (float)b1[0]) * rinv);
                hi.y = f2b(((float)a1[1] + (float)b1[1]) * rinv);
                hi.z = f2b(((float)a1[2] + (float)b1[2]) * rinv);
                hi.w = f2b(((float)a1[3] + (float)b1[3]) * rinv);
                *(ushort4*)&As[am][akc * 8]     = lo;
                *(ushort4*)&As[am][akc * 8 + 4] = hi;
            } else {
                *(uint4*)&As[am][akc * 8] =
                    *(const uint4*)(A + (size_t)arow * KK + kg);
            }
        }
        // B: 384 rows x 8 chunks = 3072 / 256 = 12 chunks/thread
#pragma unroll
        for (int u = 0; u < 12; ++u) {
            int c = tid + u * 256;
            int n = c >> 3, kc = c & 7;
            *(uint4*)&Bs[n][kc * 8] =
                *(const uint4*)(W + (size_t)n * KK + k0 + kc * 8);
        }
        __syncthreads();

        bf16x8 af0 = ld8(&As[wm + cl][kh]);
        bf16x8 af1 = ld8(&As[wm + cl][32 + kh]);
#pragma unroll
        for (int j = 0; j < 12; ++j) {
            bf16x8 b0 = ld8(&Bs[wn + 16 * j + cl][kh]);
            bf16x8 b1 = ld8(&Bs[wn + 16 * j + cl][32 + kh]);
            acc[j] = __builtin_amdgcn_mfma_f32_16x16x32_bf16(af0, b0, acc[j], 0, 0, 0);
            acc[j] = __builtin_amdgcn_mfma_f32_16x16x32_bf16(af1, b1, acc[j], 0, 0, 0);
        }
        __syncthreads();
    }

    // ---- epilogue: residual add + t write + row stats ----
    const int r0 = quad * 4;
    float v[12][4];
    float rs[4] = {0.f, 0.f, 0.f, 0.f}, rq[4] = {0.f, 0.f, 0.f, 0.f};
#pragma unroll
    for (int j = 0; j < 12; ++j) {
        int gn = wn + 16 * j + cl;
        float bn = bias[gn];
#pragma unroll
        for (int r = 0; r < 4; ++r) {
            size_t idx = (size_t)(m0g + wm + r0 + r) * EMB_ + gn;
            float vv = acc[j][r] + bn + T[idx];
            T[idx] = vv;
            v[j][r] = vv;
            rs[r] += vv;
            rq[r] += vv * vv;
        }
    }
#pragma unroll
    for (int off = 1; off < 16; off <<= 1)
#pragma unroll
        for (int r = 0; r < 4; ++r) {
            rs[r] += __shfl_xor(rs[r], off, 64);
            rq[r] += __shfl_xor(rq[r], off, 64);
        }
    if (cl == 0) {
#pragma unroll
        for (int r = 0; r < 4; ++r) {
            redS[w & 1][wm + r0 + r] = rs[r];
            redQ[w & 1][wm + r0 + r] = rq[r];
        }
    }
    __syncthreads();
#pragma unroll
    for (int r = 0; r < 4; ++r) {
        int lr = wm + r0 + r;
        float s = redS[0][lr] + redS[1][lr];
        float q = redQ[0][lr] + redQ[1][lr];
        float mu = s * (1.0f / EMB_);
        float va = fmaxf(q * (1.0f / EMB_) - mu * mu, 0.f);
        float rstd = rsqrtf(va + 1e-5f);
        u16* hr = h + (size_t)(m0g + lr) * EMB_;
#pragma unroll
        for (int j = 0; j < 12; ++j) {
            int gn = wn + 16 * j + cl;
            hr[gn] = f2b((v[j][r] - mu) * rstd * lnw[gn] + lnb[gn]);
        }
    }
}

// ============================================================
// MFMA flash attention, S^T formulation, NO-MAX softmax, split-K=2.
// grid (28, NH, B*2), block 256. Writes unnormalized O (f16) + l.
// ============================================================
__global__ __launch_bounds__(256) void attn_mfma(
    const u16* __restrict__ big, const u16* __restrict__ vT,
    u16* __restrict__ op, float* __restrict__ lp)
{
    __shared__ __align__(16) u16 qs[64][72];        // bf16 [q][d pad 64]
    __shared__ __align__(16) u16 ks[2][64][72];     // bf16 [key][d pad 64]
    __shared__ __align__(16) u16 vts[2][48][68];    // f16  [d][key]

    const int tid  = threadIdx.x;
    const int lane = tid & 63, wave = tid >> 6;
    const int t = lane & 15, quad = lane >> 4;
    const int q0 = blockIdx.x * 64, h = blockIdx.y;
    const int b = blockIdx.z >> 1, sp = blockIdx.z & 1;
    const int tile0 = sp * 14;
    const u16* rowb = big + (size_t)b * BSTR * 1152;
    const u16* vTb  = vT + ((size_t)(b * 8 + h) * 48) * BSTR;

    {
        uint4 z = make_uint4(0, 0, 0, 0);
        for (int c = tid; c < 384; c += 256) {
            int reg = c >> 7, idx = c & 127;
            int rr = idx >> 1, hb = idx & 1;
            if (reg == 0) *(uint4*)&qs[rr][48 + hb * 8] = z;
            else          *(uint4*)&ks[reg - 1][rr][48 + hb * 8] = z;
        }
    }
    for (int c = tid; c < 384; c += 256) {
        int tok = c / 6, ch = c % 6;
        int n = q0 + tok;
        uint4 v = make_uint4(0, 0, 0, 0);
        if (n < NTOK)
            v = *(const uint4*)(rowb + (size_t)n * 1152 + h * 48 + ch * 8);
        *(uint4*)&qs[tok][ch * 8] = v;
    }

    const int c1v = tid + 256;
    const int ktok0 = tid / 6, kch0 = tid % 6;
    const int ktok1 = c1v / 6, kch1 = c1v % 6;
    const int vd0 = tid >> 3,  vch0 = tid & 7;
    const int vd1 = (c1v) >> 3, vch1 = c1v & 7;
    const bool two = (tid < 128);
    uint4 kr0, kr1, vr0, vr1;

#define PREFETCH(K0)                                                          \
    {                                                                         \
        int n0 = (K0) + ktok0;                                                \
        kr0 = (n0 < NTOK) ? *(const uint4*)(rowb + (size_t)n0 * 1152 + 384 +  \
                                            h * 48 + kch0 * 8)                \
                          : make_uint4(0, 0, 0, 0);                           \
        vr0 = *(const uint4*)(vTb + (size_t)vd0 * BSTR + (K0) + vch0 * 8);    \
        if (two) {                                                            \
            int n1 = (K0) + ktok1;                                            \
            kr1 = (n1 < NTOK) ? *(const uint4*)(rowb + (size_t)n1 * 1152 +    \
                                                384 + h * 48 + kch1 * 8)      \
                              : make_uint4(0, 0, 0, 0);                       \
            vr1 = *(const uint4*)(vTb + (size_t)vd1 * BSTR + (K0) + vch1 * 8);\
        }                                                                     \
    }
#define COMMIT(BUF)                                                           \
    {                                                                         \
        *(uint4*)&ks[BUF][ktok0][kch0 * 8] = kr0;                             \
        *(uint4*)&vts[BUF][vd0][vch0 * 8] = vr0;                              \
        if (two) {                                                            \
            *(uint4*)&ks[BUF][ktok1][kch1 * 8] = kr1;                         \
            *(uint4*)&vts[BUF][vd1][vch1 * 8] = vr1;                          \
        }                                                                     \
    }

    PREFETCH(tile0 * 64);
    COMMIT(0);
    __syncthreads();

    float l_lane = 0.f;
    floatx4 oacc[3];
#pragma unroll
    for (int dt = 0; dt < 3; ++dt) oacc[dt] = (floatx4){0.f, 0.f, 0.f, 0.f};

    for (int it = 0; it < 14; ++it) {
        const int k0 = (tile0 + it) * 64;
        const int cur = it & 1, nxt = cur ^ 1;
        if (it < 13) PREFETCH(k0 + 64);

        floatx4 sf[4];
#pragma unroll
        for (int f = 0; f < 4; ++f) sf[f] = (floatx4){0.f, 0.f, 0.f, 0.f};
        bf16x8 qb0 = ld8(&qs[wave * 16 + t][quad * 8]);
        bf16x8 qb1 = ld8(&qs[wave * 16 + t][32 + quad * 8]);
#pragma unroll
        for (int f = 0; f < 4; ++f) {
            bf16x8 ka0 = ld8(&ks[cur][f * 16 + t][quad * 8]);
            bf16x8 ka1 = ld8(&ks[cur][f * 16 + t][32 + quad * 8]);
            sf[f] = __builtin_amdgcn_mfma_f32_16x16x32_bf16(ka0, qb0, sf[f], 0, 0, 0);
            sf[f] = __builtin_amdgcn_mfma_f32_16x16x32_bf16(ka1, qb1, sf[f], 0, 0, 0);
        }
        if (k0 + 64 > NTOK) {
#pragma unroll
            for (int f = 0; f < 4; ++f)
#pragma unroll
                for (int r = 0; r < 4; ++r) {
                    bool valid = (k0 + f * 16 + quad * 4 + r) < NTOK;
                    if (!valid) sf[f][r] = -1e30f;
                }
        }
#pragma unroll
        for (int f = 0; f < 4; ++f)
#pragma unroll
            for (int r = 0; r < 4; ++r) {
                sf[f][r] = exp2f(sf[f][r] * SCALE2_);
                l_lane += sf[f][r];
            }

#pragma unroll
        for (int f = 0; f < 4; ++f) {
            halfx4 pa;
            pa[0] = (_Float16)sf[f][0]; pa[1] = (_Float16)sf[f][1];
            pa[2] = (_Float16)sf[f][2]; pa[3] = (_Float16)sf[f][3];
#pragma unroll
            for (int dt = 0; dt < 3; ++dt) {
                ushort4 vv = *(const ushort4*)&vts[cur][dt * 16 + t][f * 16 + quad * 4];
                halfx4 vb = __builtin_bit_cast(halfx4, vv);
                oacc[dt] = __builtin_amdgcn_mfma_f32_16x16x16f16(pa, vb, oacc[dt], 0, 0, 0);
            }
        }

        if (it < 13) COMMIT(nxt);
        __syncthreads();
    }
#undef PREFETCH
#undef COMMIT

    l_lane += __shfl_xor(l_lane, 16, 64);
    l_lane += __shfl_xor(l_lane, 32, 64);
    if (quad == 0)
        lp[((size_t)(sp * B_ + b) * BSTR + q0 + wave * 16 + t) * NH_ + h] = l_lane;

#pragma unroll
    for (int r = 0; r < 4; ++r) {
        int n = q0 + wave * 16 + quad * 4 + r;     // < BSTR always
#pragma unroll
        for (int dt = 0; dt < 3; ++dt)
            op[((size_t)(sp * B_ + b) * BSTR + n) * EMB_ + h * 48 + dt * 16 + t] =
                f2h(oacc[dt][r]);
    }
}

// ============================================================
// Head: h already holds final-LN rows (mlp2 l=5 epilogue used norm_w/b).
// out[b][c] = h[row0_b] . head_w[c] + head_b[c]. grid B, block 384.
// ============================================================
__global__ __launch_bounds__(384) void head_kernel(
    const u16* __restrict__ h, const float* __restrict__ hw,
    const float* __restrict__ hb, float* __restrict__ out)
{
    const int b = blockIdx.x;
    const int e = threadIdx.x;
    const int wave = e >> 6, lane = e & 63;
    __shared__ float red[6];

    float v = b2f(h[(size_t)b * BSTR * EMB_ + e]);

    for (int c = 0; c < NC_; ++c) {
        float p = v * hw[c * EMB_ + e];
#pragma unroll
        for (int off = 32; off; off >>= 1) p += __shfl_xor(p, off, 64);
        __syncthreads();
        if (lane == 0) red[wave] = p;
        __syncthreads();
        if (e == 0) {
            float sum = 0.f;
            for (int w2 = 0; w2 < 6; ++w2) sum += red[w2];
            out[b * NC_ + c] = sum + hb[c];
        }
    }
}

// ============================================================
extern "C" void kernel_launch(void* const* d_in, const int* in_sizes, int n_in,
                              void* d_out, int out_size, void* d_ws, size_t ws_size,
                              hipStream_t stream)
{
    const float* x         = (const float*)d_in[0];
    const float* conv_w    = (const float*)d_in[1];
    const float* conv_b    = (const float*)d_in[2];
    const float* cls_token = (const float*)d_in[3];
    const float* pos_embed = (const float*)d_in[4];
    const float* ln1_w     = (const float*)d_in[5];
    const float* ln1_b     = (const float*)d_in[6];
    const float* qkv_w     = (const float*)d_in[7];
    const float* qkv_b     = (const float*)d_in[8];
    const float* proj_w    = (const float*)d_in[9];
    const float* proj_b    = (const float*)d_in[10];
    const float* ln2_w     = (const float*)d_in[11];
    const float* ln2_b     = (const float*)d_in[12];
    const float* mlp_w1    = (const float*)d_in[13];
    const float* mlp_b1    = (const float*)d_in[14];
    const float* mlp_w2    = (const float*)d_in[15];
    const float* mlp_b2    = (const float*)d_in[16];
    const float* norm_w    = (const float*)d_in[17];
    const float* norm_b    = (const float*)d_in[18];
    const float* head_w    = (const float*)d_in[19];
    const float* head_b    = (const float*)d_in[20];
    float* out = (float*)d_out;

    // ---- workspace layout ----
    char* p = (char*)d_ws;
    float* t  = (float*)p;  p += (size_t)M_PAD * EMB_ * 4;   // fp32 residual
    u16* h    = (u16*)p;    p += (size_t)M_PAD * EMB_ * 2;   // bf16 LN out
    u16* big  = (u16*)p;    p += (size_t)M_PAD * MLP_ * 2;   // bf16 qkv / mlp hidden
    u16* wqb  = (u16*)p;    p += (size_t)NL_ * 1152 * EMB_ * 2;
    u16* wpb  = (u16*)p;    p += (size_t)NL_ * EMB_ * EMB_ * 2;
    u16* w1b  = (u16*)p;    p += (size_t)NL_ * MLP_ * EMB_ * 2;
    u16* w2b  = (u16*)p;    p += (size_t)NL_ * EMB_ * MLP_ * 2;
    u16* cwb  = (u16*)p;    p += (size_t)CW_N * 2;           // bf16 conv_w
    u16* xb   = (u16*)p;    p += (size_t)B_ * 96 * 96 * 96 * 2;  // bf16 x
    u16* op   = (u16*)p;    p += 2 * OPSZ * 2;               // f16 partial O (2 splits)
    float* lp = (float*)p;  p += (size_t)2 * B_ * BSTR * NH_ * 4; // f32 partial l
    // vT (f16) lives in big's unused tail (16 heads * 48 d * 1792 tok)
    u16* vT = big + (size_t)M_PAD * 1152;

    cvt_all<<<P5_ / 4 / 256, 256, 0, stream>>>(
        conv_w, x, qkv_w, proj_w, mlp_w1, mlp_w2,
        cwb, xb, wqb, wpb, w1b, w2b);

    patch_mfma<<<dim3(EMB_ / 64, 3456 / 64), 256, 0, stream>>>(
        xb, cwb, conv_b, cls_token, pos_embed, t);

    // layer 0's LN1 (later layers get LN1 from mlp2 epilogue)
    ln_kernel<<<dim3((NTOK + 3) / 4, B_), 256, 0, stream>>>(
        t, ln1_w, ln1_b, h);

    for (int l = 0; l < NL_; ++l) {
        // qkv: Q,K -> big (bf16); V -> vT (f16 transposed). 64x128 tiles, BK=64.
        gemm2<2, 4, 0, 1><<<dim3(1152 / 128, M_PAD / 64), 256, 0, stream>>>(
            h, wqb + (size_t)l * 1152 * EMB_, qkv_b + l * 1152, big, vT, 1152, EMB_);
        attn_mfma<<<dim3(BSTR / 64, NH_, B_ * 2), 256, 0, stream>>>(big, vT, op, lp);
        // proj: t += combine(op) @ proj_w^T + b; h = LN2(t)
        gemm_row<1, EMB_><<<M_PAD / 32, 256, 0, stream>>>(
            big, op, lp, wpb + (size_t)l * EMB_ * EMB_, proj_b + l * EMB_,
            t, ln2_w + l * EMB_, ln2_b + l * EMB_, h);
        // mlp1: big = gelu(h @ mlp_w1^T + b). 64x128 tiles, BK=64.
        gemm2<2, 4, 1, 0><<<dim3(MLP_ / 128, M_PAD / 64), 256, 0, stream>>>(
            h, w1b + (size_t)l * MLP_ * EMB_, mlp_b1 + l * MLP_, big, nullptr,
            MLP_, EMB_);
        // mlp2: t += big @ mlp_w2^T + b; h = LN1[l+1](t) (or final norm at l=5)
        const float* nlw = (l < NL_ - 1) ? (ln1_w + (l + 1) * EMB_) : norm_w;
        const float* nlb = (l < NL_ - 1) ? (ln1_b + (l + 1) * EMB_) : norm_b;
        gemm_row<0, MLP_><<<M_PAD / 32, 256, 0, stream>>>(
            big, nullptr, nullptr, w2b + (size_t)l * EMB_ * MLP_,
            mlp_b2 + l * EMB_, t, nlw, nlb, h);
    }

    head_kernel<<<B_, 384, 0, stream>>>(h, head_w, head_b, out);
}